// Round 3
// baseline (644.416 us; speedup 1.0000x reference)
//
#include <hip/hip_runtime.h>
#include <hip/hip_bf16.h>

constexpr int MTOK = 1024;   // B*S
constexpr int HDIM = 2048;
constexpr int IDIM = 2048;
constexpr int NEXP = 16;
constexpr int TOPK = 4;
constexpr int NA   = MTOK * TOPK;   // 4096 assignments

#define ALPHA_C 1.702f
#define LIMIT_C 7.0f
#define RMS_EPS 1e-5f

using short8   = __attribute__((ext_vector_type(8))) short;
using f32x4    = __attribute__((ext_vector_type(4))) float;

__device__ __forceinline__ unsigned short f2bf(float f) {
    unsigned u = __builtin_bit_cast(unsigned, f);
    u += 0x7fffu + ((u >> 16) & 1u);     // round-to-nearest-even
    return (unsigned short)(u >> 16);
}

__device__ __forceinline__ unsigned pack2bf(float lo, float hi) {
    return (unsigned)f2bf(lo) | ((unsigned)f2bf(hi) << 16);
}

// pack 8 f32 -> 8 bf16 (RNE)
__device__ __forceinline__ short8 cvt8(const float4 a, const float4 b) {
    union { short8 s; unsigned u[4]; } r;
    r.u[0] = pack2bf(a.x, a.y);
    r.u[1] = pack2bf(a.z, a.w);
    r.u[2] = pack2bf(b.x, b.y);
    r.u[3] = pack2bf(b.z, b.w);
    return r.s;
}

// ---------------- out = x ----------------
__global__ void k_copy(const float* __restrict__ x, float* __restrict__ out, int n4) {
    int i = blockIdx.x * blockDim.x + threadIdx.x;
    int stride = gridDim.x * blockDim.x;
    const float4* xs = (const float4*)x;
    float4* os = (float4*)out;
    for (; i < n4; i += stride) os[i] = xs[i];
}

// ---------------- RMSNorm + router + top-k ----------------
__global__ __launch_bounds__(256) void k_router(
    const float* __restrict__ x, const float* __restrict__ norm_w,
    const float* __restrict__ gate_w, const float* __restrict__ gate_b,
    unsigned short* __restrict__ t_bf,
    int* __restrict__ counts, int* __restrict__ idx_of,
    int* __restrict__ slot_of, float* __restrict__ gate_mk)
{
    __shared__ float t_lds[HDIM];
    __shared__ float red[4];
    __shared__ float logits[NEXP];

    const int m   = blockIdx.x;
    const int tid = threadIdx.x;
    const float* xr = x + (size_t)m * HDIM;

    float4 v0 = ((const float4*)xr)[tid * 2];
    float4 v1 = ((const float4*)xr)[tid * 2 + 1];
    float ss = v0.x*v0.x + v0.y*v0.y + v0.z*v0.z + v0.w*v0.w
             + v1.x*v1.x + v1.y*v1.y + v1.z*v1.z + v1.w*v1.w;
    #pragma unroll
    for (int off = 32; off > 0; off >>= 1) ss += __shfl_down(ss, off);
    if ((tid & 63) == 0) red[tid >> 6] = ss;
    __syncthreads();
    float tot = red[0] + red[1] + red[2] + red[3];
    float scale = rsqrtf(tot / (float)HDIM + RMS_EPS);

    float4 n0 = ((const float4*)norm_w)[tid * 2];
    float4 n1 = ((const float4*)norm_w)[tid * 2 + 1];
    float t[8];
    t[0]=v0.x*scale*n0.x; t[1]=v0.y*scale*n0.y; t[2]=v0.z*scale*n0.z; t[3]=v0.w*scale*n0.w;
    t[4]=v1.x*scale*n1.x; t[5]=v1.y*scale*n1.y; t[6]=v1.z*scale*n1.z; t[7]=v1.w*scale*n1.w;
    short8 pk;
    #pragma unroll
    for (int j = 0; j < 8; ++j) {
        t_lds[tid * 8 + j] = t[j];
        pk[j] = (short)f2bf(t[j]);
    }
    *(short8*)(t_bf + (size_t)m * HDIM + tid * 8) = pk;
    __syncthreads();

    const int e = tid >> 4, j = tid & 15;
    const float* gw = gate_w + (size_t)e * HDIM;
    float part = 0.f;
    for (int h = j; h < HDIM; h += 16) part += t_lds[h] * gw[h];
    #pragma unroll
    for (int off = 8; off > 0; off >>= 1) part += __shfl_xor(part, off);
    if (j == 0) logits[e] = part + gate_b[e];
    __syncthreads();

    if (tid == 0) {
        float lv[NEXP];
        #pragma unroll
        for (int q = 0; q < NEXP; ++q) lv[q] = logits[q];
        int   sel[TOPK];
        float sv[TOPK];
        #pragma unroll
        for (int k = 0; k < TOPK; ++k) {
            float best = -1e30f; int bi = 0;
            for (int q = 0; q < NEXP; ++q)
                if (lv[q] > best) { best = lv[q]; bi = q; }
            sel[k] = bi; sv[k] = best; lv[bi] = -1e30f;
        }
        float mx = sv[0], s = 0.f, g[TOPK];
        #pragma unroll
        for (int k = 0; k < TOPK; ++k) { g[k] = __expf(sv[k] - mx); s += g[k]; }
        float inv = 1.f / s;
        #pragma unroll
        for (int k = 0; k < TOPK; ++k) {
            int a = m * TOPK + k;
            int slot = atomicAdd(&counts[sel[k]], 1);
            idx_of[a]  = sel[k];
            slot_of[a] = slot;
            gate_mk[a] = g[k] * inv;
        }
    }
}

__global__ void k_offsets(const int* __restrict__ counts, int* __restrict__ offsets) {
    if (threadIdx.x == 0) {
        int s = 0;
        for (int e = 0; e < NEXP; ++e) { offsets[e] = s; s += counts[e]; }
        offsets[NEXP] = s;
    }
}

__global__ void k_remap(const int* __restrict__ idx_of, const int* __restrict__ slot_of,
                        const float* __restrict__ gate_mk, const int* __restrict__ offsets,
                        int* __restrict__ token_of, float* __restrict__ gate_row)
{
    int a = blockIdx.x * blockDim.x + threadIdx.x;
    if (a >= NA) return;
    int e = idx_of[a];
    int r = offsets[e] + slot_of[a];
    token_of[r] = a >> 2;
    gate_row[r] = gate_mk[a];
}

// ---------------- GEMM1 + bias + clamped SwiGLU -> act (bf16) ----------------
// BM=320 rows (covers a whole expert w.h.p. -> each w1 byte read once).
// Block: 256 thr = 4 waves; wave wv owns rows [wv*80, wv*80+80) x 64 o-cols.
// 64 o-cols = 32 i-values: rows 0..31 of lB are o=2i (a), 32..63 are o=2i+1 (b).
__global__ __launch_bounds__(256) void k_gemm1(
    const unsigned short* __restrict__ t_bf,
    const float* __restrict__ w1, const float* __restrict__ b1,
    const int* __restrict__ counts, const int* __restrict__ offsets,
    const int* __restrict__ token_of,
    unsigned short* __restrict__ act)
{
    constexpr int BM = 320, LD = 80;           // LD bytes: 2-way bank alias only
    __shared__ unsigned char lA[BM * LD];      // 25600 B
    __shared__ unsigned char lB[64 * LD];      // 5120 B

    const int e  = blockIdx.z;
    const int ne = counts[e];
    const int brow = blockIdx.y * BM;
    if (brow >= ne) return;
    const int roff = offsets[e];
    const int i0 = blockIdx.x * 32;
    const int tid = threadIdx.x;

    const int ap = tid & 3, arow = tid >> 2;   // staging: 16B chunk ap of row arow(+64*it)
    const unsigned short* aptr[5];
    #pragma unroll
    for (int it = 0; it < 5; ++it) {
        int rr = brow + arow + it * 64;
        aptr[it] = (rr < ne) ? (t_bf + (size_t)token_of[roff + rr] * HDIM) : nullptr;
    }
    const int bj = arow;                        // B row 0..63
    const int o  = (bj < 32) ? (2 * (i0 + bj)) : (2 * (i0 + bj - 32) + 1);
    const float* bsrc = w1 + ((size_t)e * (2 * IDIM) + o) * HDIM;

    const int wv = tid >> 6, ln = tid & 63;
    const int lr = ln & 15, lk = ln >> 4;

    f32x4 acc[5][4] = {};
    for (int k0 = 0; k0 < HDIM; k0 += 32) {
        __syncthreads();
        #pragma unroll
        for (int it = 0; it < 5; ++it) {
            short8 av = {};
            if (aptr[it]) av = *(const short8*)(aptr[it] + k0 + ap * 8);
            *(short8*)(lA + (arow + it * 64) * LD + ap * 16) = av;
        }
        float4 bv0 = *(const float4*)(bsrc + k0 + ap * 8);
        float4 bv1 = *(const float4*)(bsrc + k0 + ap * 8 + 4);
        *(short8*)(lB + bj * LD + ap * 16) = cvt8(bv0, bv1);
        __syncthreads();

        short8 afr[5], bfr[4];
        #pragma unroll
        for (int mf = 0; mf < 5; ++mf)
            afr[mf] = *(const short8*)(lA + (wv * 80 + mf * 16 + lr) * LD + lk * 16);
        #pragma unroll
        for (int n = 0; n < 4; ++n)
            bfr[n] = *(const short8*)(lB + (n * 16 + lr) * LD + lk * 16);
        #pragma unroll
        for (int mf = 0; mf < 5; ++mf)
            #pragma unroll
            for (int n = 0; n < 4; ++n)
                acc[mf][n] = __builtin_amdgcn_mfma_f32_16x16x32_bf16(afr[mf], bfr[n], acc[mf][n], 0, 0, 0);
    }

    #pragma unroll
    for (int n = 0; n < 2; ++n) {
        const int i = i0 + n * 16 + lr;
        const float ba = b1[(size_t)e * (2 * IDIM) + 2 * i];
        const float bb = b1[(size_t)e * (2 * IDIM) + 2 * i + 1];
        #pragma unroll
        for (int mf = 0; mf < 5; ++mf) {
            #pragma unroll
            for (int r = 0; r < 4; ++r) {
                const int rg = brow + wv * 80 + mf * 16 + lk * 4 + r;
                if (rg < ne) {
                    float ha = acc[mf][n][r] + ba;
                    float hb = acc[mf][n + 2][r] + bb;
                    float a = fminf(ha, LIMIT_C);
                    float b = fminf(fmaxf(hb, -LIMIT_C), LIMIT_C);
                    float s = 1.f / (1.f + __expf(-ALPHA_C * a));
                    act[(size_t)(roff + rg) * IDIM + i] = f2bf(a * s * (b + 1.f));
                }
            }
        }
    }
}

// ---------------- GEMM2 + bias, gate-scale, atomic combine ----------------
// Same skeleton; K split in 2 for occupancy (bias applied on split 0 only).
__global__ __launch_bounds__(256) void k_gemm2(
    const unsigned short* __restrict__ act,
    const float* __restrict__ w2, const float* __restrict__ b2,
    const int* __restrict__ counts, const int* __restrict__ offsets,
    const int* __restrict__ token_of, const float* __restrict__ gate_row,
    float* __restrict__ out)
{
    constexpr int BM = 320, LD = 80;
    __shared__ unsigned char lA[BM * LD];
    __shared__ unsigned char lB[64 * LD];

    const int e  = blockIdx.z;
    const int ne = counts[e];
    const int brow = blockIdx.y * BM;
    if (brow >= ne) return;
    const int roff = offsets[e];
    const int ks = blockIdx.x & 1;
    const int d0 = (blockIdx.x >> 1) * 64;
    const int tid = threadIdx.x;

    const int ap = tid & 3, arow = tid >> 2;
    const unsigned short* aptr[5];
    #pragma unroll
    for (int it = 0; it < 5; ++it) {
        int rr = brow + arow + it * 64;
        aptr[it] = (rr < ne) ? (act + (size_t)(roff + rr) * IDIM) : nullptr;
    }
    const float* bsrc = w2 + ((size_t)e * HDIM + d0 + arow) * IDIM;

    const int wv = tid >> 6, ln = tid & 63;
    const int lr = ln & 15, lk = ln >> 4;

    f32x4 acc[5][4] = {};
    const int kbeg = ks * (IDIM / 2), kend = kbeg + IDIM / 2;
    for (int k0 = kbeg; k0 < kend; k0 += 32) {
        __syncthreads();
        #pragma unroll
        for (int it = 0; it < 5; ++it) {
            short8 av = {};
            if (aptr[it]) av = *(const short8*)(aptr[it] + k0 + ap * 8);
            *(short8*)(lA + (arow + it * 64) * LD + ap * 16) = av;
        }
        float4 bv0 = *(const float4*)(bsrc + k0 + ap * 8);
        float4 bv1 = *(const float4*)(bsrc + k0 + ap * 8 + 4);
        *(short8*)(lB + arow * LD + ap * 16) = cvt8(bv0, bv1);
        __syncthreads();

        short8 afr[5], bfr[4];
        #pragma unroll
        for (int mf = 0; mf < 5; ++mf)
            afr[mf] = *(const short8*)(lA + (wv * 80 + mf * 16 + lr) * LD + lk * 16);
        #pragma unroll
        for (int n = 0; n < 4; ++n)
            bfr[n] = *(const short8*)(lB + (n * 16 + lr) * LD + lk * 16);
        #pragma unroll
        for (int mf = 0; mf < 5; ++mf)
            #pragma unroll
            for (int n = 0; n < 4; ++n)
                acc[mf][n] = __builtin_amdgcn_mfma_f32_16x16x32_bf16(afr[mf], bfr[n], acc[mf][n], 0, 0, 0);
    }

    #pragma unroll
    for (int mf = 0; mf < 5; ++mf) {
        #pragma unroll
        for (int r = 0; r < 4; ++r) {
            const int rg = brow + wv * 80 + mf * 16 + lk * 4 + r;
            if (rg >= ne) continue;
            const int tok = token_of[roff + rg];
            const float g = gate_row[roff + rg];
            float* orow = out + (size_t)tok * HDIM;
            #pragma unroll
            for (int n = 0; n < 4; ++n) {
                const int d = d0 + n * 16 + lr;
                float v = g * acc[mf][n][r];
                if (ks == 0) v += g * b2[(size_t)e * HDIM + d];
                atomicAdd(orow + d, v);
            }
        }
    }
}

extern "C" void kernel_launch(void* const* d_in, const int* in_sizes, int n_in,
                              void* d_out, int out_size, void* d_ws, size_t ws_size,
                              hipStream_t stream) {
    const float* x      = (const float*)d_in[0];
    const float* norm_w = (const float*)d_in[1];
    const float* gate_w = (const float*)d_in[2];
    const float* gate_b = (const float*)d_in[3];
    const float* w1     = (const float*)d_in[4];
    const float* b1     = (const float*)d_in[5];
    const float* w2     = (const float*)d_in[6];
    const float* b2     = (const float*)d_in[7];
    float* out = (float*)d_out;

    char* ws = (char*)d_ws;
    size_t off = 0;
    unsigned short* t_bf = (unsigned short*)(ws + off); off += (size_t)MTOK * HDIM * 2;  // 4 MB
    unsigned short* actb = (unsigned short*)(ws + off); off += (size_t)NA * IDIM * 2;    // 16.8 MB
    int*   counts   = (int*)(ws + off);   off += 256;
    int*   offsets  = (int*)(ws + off);   off += 256;
    int*   idx_of   = (int*)(ws + off);   off += (size_t)NA * 4;
    int*   slot_of  = (int*)(ws + off);   off += (size_t)NA * 4;
    float* gate_mk  = (float*)(ws + off); off += (size_t)NA * 4;
    int*   token_of = (int*)(ws + off);   off += (size_t)NA * 4;
    float* gate_row = (float*)(ws + off); off += (size_t)NA * 4;

    (void)hipMemsetAsync(counts, 0, 256, stream);
    k_copy<<<1024, 256, 0, stream>>>(x, out, MTOK * HDIM / 4);
    k_router<<<MTOK, 256, 0, stream>>>(x, norm_w, gate_w, gate_b, t_bf,
                                       counts, idx_of, slot_of, gate_mk);
    k_offsets<<<1, 64, 0, stream>>>(counts, offsets);
    k_remap<<<NA / 256, 256, 0, stream>>>(idx_of, slot_of, gate_mk, offsets,
                                          token_of, gate_row);
    // y covers worst-case ne (<= MTOK); blocks beyond ne exit immediately
    k_gemm1<<<dim3(IDIM / 32, (MTOK + 319) / 320, NEXP), 256, 0, stream>>>(
        t_bf, w1, b1, counts, offsets, token_of, actb);
    k_gemm2<<<dim3((HDIM / 64) * 2, (MTOK + 319) / 320, NEXP), 256, 0, stream>>>(
        actb, w2, b2, counts, offsets, token_of, gate_row, out);
}

// Round 4
// 617.781 us; speedup vs baseline: 1.0431x; 1.0431x over previous
//
#include <hip/hip_runtime.h>
#include <hip/hip_bf16.h>

constexpr int MTOK = 1024;   // B*S
constexpr int HDIM = 2048;
constexpr int IDIM = 2048;
constexpr int NEXP = 16;
constexpr int TOPK = 4;
constexpr int NA   = MTOK * TOPK;   // 4096 assignments

#define ALPHA_C 1.702f
#define LIMIT_C 7.0f
#define RMS_EPS 1e-5f

using short8   = __attribute__((ext_vector_type(8))) short;
using f32x4    = __attribute__((ext_vector_type(4))) float;

__device__ __forceinline__ unsigned short f2bf(float f) {
    unsigned u = __builtin_bit_cast(unsigned, f);
    u += 0x7fffu + ((u >> 16) & 1u);     // round-to-nearest-even
    return (unsigned short)(u >> 16);
}

__device__ __forceinline__ unsigned pack2bf(float lo, float hi) {
    return (unsigned)f2bf(lo) | ((unsigned)f2bf(hi) << 16);
}

// pack 8 f32 -> 8 bf16 (RNE)
__device__ __forceinline__ short8 cvt8(const float4 a, const float4 b) {
    union { short8 s; unsigned u[4]; } r;
    r.u[0] = pack2bf(a.x, a.y);
    r.u[1] = pack2bf(a.z, a.w);
    r.u[2] = pack2bf(b.x, b.y);
    r.u[3] = pack2bf(b.z, b.w);
    return r.s;
}

// async global->LDS, 16B per lane; lds dest = wave-uniform base + lane*16
__device__ __forceinline__ void gload16(const void* g, void* l) {
    __builtin_amdgcn_global_load_lds(
        (const __attribute__((address_space(1))) void*)g,
        (__attribute__((address_space(3))) void*)l, 16, 0, 0);
}

// ---------------- out = x ----------------
__global__ void k_copy(const float* __restrict__ x, float* __restrict__ out, int n4) {
    int i = blockIdx.x * blockDim.x + threadIdx.x;
    int stride = gridDim.x * blockDim.x;
    const float4* xs = (const float4*)x;
    float4* os = (float4*)out;
    for (; i < n4; i += stride) os[i] = xs[i];
}

// ---------------- RMSNorm + router + top-k ----------------
__global__ __launch_bounds__(256) void k_router(
    const float* __restrict__ x, const float* __restrict__ norm_w,
    const float* __restrict__ gate_w, const float* __restrict__ gate_b,
    unsigned short* __restrict__ t_bf,
    int* __restrict__ counts, int* __restrict__ idx_of,
    int* __restrict__ slot_of, float* __restrict__ gate_mk)
{
    __shared__ float t_lds[HDIM];
    __shared__ float red[4];
    __shared__ float logits[NEXP];

    const int m   = blockIdx.x;
    const int tid = threadIdx.x;
    const float* xr = x + (size_t)m * HDIM;

    float4 v0 = ((const float4*)xr)[tid * 2];
    float4 v1 = ((const float4*)xr)[tid * 2 + 1];
    float ss = v0.x*v0.x + v0.y*v0.y + v0.z*v0.z + v0.w*v0.w
             + v1.x*v1.x + v1.y*v1.y + v1.z*v1.z + v1.w*v1.w;
    #pragma unroll
    for (int off = 32; off > 0; off >>= 1) ss += __shfl_down(ss, off);
    if ((tid & 63) == 0) red[tid >> 6] = ss;
    __syncthreads();
    float tot = red[0] + red[1] + red[2] + red[3];
    float scale = rsqrtf(tot / (float)HDIM + RMS_EPS);

    float4 n0 = ((const float4*)norm_w)[tid * 2];
    float4 n1 = ((const float4*)norm_w)[tid * 2 + 1];
    float t[8];
    t[0]=v0.x*scale*n0.x; t[1]=v0.y*scale*n0.y; t[2]=v0.z*scale*n0.z; t[3]=v0.w*scale*n0.w;
    t[4]=v1.x*scale*n1.x; t[5]=v1.y*scale*n1.y; t[6]=v1.z*scale*n1.z; t[7]=v1.w*scale*n1.w;
    short8 pk;
    #pragma unroll
    for (int j = 0; j < 8; ++j) {
        t_lds[tid * 8 + j] = t[j];
        pk[j] = (short)f2bf(t[j]);
    }
    *(short8*)(t_bf + (size_t)m * HDIM + tid * 8) = pk;
    __syncthreads();

    const int e = tid >> 4, j = tid & 15;
    const float* gw = gate_w + (size_t)e * HDIM;
    float part = 0.f;
    for (int h = j; h < HDIM; h += 16) part += t_lds[h] * gw[h];
    #pragma unroll
    for (int off = 8; off > 0; off >>= 1) part += __shfl_xor(part, off);
    if (j == 0) logits[e] = part + gate_b[e];
    __syncthreads();

    if (tid == 0) {
        float lv[NEXP];
        #pragma unroll
        for (int q = 0; q < NEXP; ++q) lv[q] = logits[q];
        int   sel[TOPK];
        float sv[TOPK];
        #pragma unroll
        for (int k = 0; k < TOPK; ++k) {
            float best = -1e30f; int bi = 0;
            for (int q = 0; q < NEXP; ++q)
                if (lv[q] > best) { best = lv[q]; bi = q; }
            sel[k] = bi; sv[k] = best; lv[bi] = -1e30f;
        }
        float mx = sv[0], s = 0.f, g[TOPK];
        #pragma unroll
        for (int k = 0; k < TOPK; ++k) { g[k] = __expf(sv[k] - mx); s += g[k]; }
        float inv = 1.f / s;
        #pragma unroll
        for (int k = 0; k < TOPK; ++k) {
            int a = m * TOPK + k;
            int slot = atomicAdd(&counts[sel[k]], 1);
            idx_of[a]  = sel[k];
            slot_of[a] = slot;
            gate_mk[a] = g[k] * inv;
        }
    }
}

__global__ void k_offsets(const int* __restrict__ counts, int* __restrict__ offsets) {
    if (threadIdx.x == 0) {
        int s = 0;
        for (int e = 0; e < NEXP; ++e) { offsets[e] = s; s += counts[e]; }
        offsets[NEXP] = s;
    }
}

__global__ void k_remap(const int* __restrict__ idx_of, const int* __restrict__ slot_of,
                        const float* __restrict__ gate_mk, const int* __restrict__ offsets,
                        int* __restrict__ token_of, float* __restrict__ gate_row)
{
    int a = blockIdx.x * blockDim.x + threadIdx.x;
    if (a >= NA) return;
    int e = idx_of[a];
    int r = offsets[e] + slot_of[a];
    token_of[r] = a >> 2;
    gate_row[r] = gate_mk[a];
}

// ---------------- GEMM1 + bias + clamped SwiGLU -> act (bf16) ----------------
// BM=320 rows; 4 waves; wave wv: rows [wv*80, wv*80+80) x 64 o-cols.
// lA layout K-chunk-major: [kc(4)][row(320)][16B] -> gload_lds linear dest,
// fragment reads 2-way bank alias only. Double-buffered, 1 barrier / K-step.
__global__ __launch_bounds__(256, 3) void k_gemm1(
    const unsigned short* __restrict__ t_bf,
    const float* __restrict__ w1, const float* __restrict__ b1,
    const int* __restrict__ counts, const int* __restrict__ offsets,
    const int* __restrict__ token_of,
    unsigned short* __restrict__ act)
{
    __shared__ unsigned char lA[2][20480];   // [kc4][320][16]
    __shared__ unsigned char lB[2][5120];    // [64][80]

    const int e  = blockIdx.z;
    const int ne = counts[e];
    const int brow = blockIdx.y * 320;
    if (brow >= ne) return;
    const int roff = offsets[e];
    const int i0 = blockIdx.x * 32;
    const int tid = threadIdx.x;

    const int wv = tid >> 6, ln = tid & 63;
    const int lr = ln & 15, lk = ln >> 4;
    const int bj = tid >> 2, bp = tid & 3;

    // A per-lane gathered sources (wave wv stages K-chunk wv for 64 rows / it)
    const unsigned short* asrc[5];
    #pragma unroll
    for (int it = 0; it < 5; ++it) {
        int rr = brow + it * 64 + ln;
        int tok = (rr < ne) ? token_of[roff + rr] : token_of[roff];
        asrc[it] = t_bf + (size_t)tok * HDIM + wv * 8;
    }
    const int o = (bj < 32) ? (2 * (i0 + bj)) : (2 * (i0 + bj - 32) + 1);
    const float* bsrc = w1 + ((size_t)e * (2 * IDIM) + o) * HDIM + bp * 8;

    f32x4 acc[5][4] = {};

    // prologue: stage tile 0
    {
        float4 v0 = *(const float4*)(bsrc);
        float4 v1 = *(const float4*)(bsrc + 4);
        #pragma unroll
        for (int it = 0; it < 5; ++it)
            gload16(asrc[it], &lA[0][(wv * 320 + it * 64) * 16]);
        *(short8*)(&lB[0][bj * 80 + bp * 16]) = cvt8(v0, v1);
    }
    __syncthreads();

    for (int t = 0; t < 64; ++t) {
        const int c = t & 1;
        unsigned char* cA = lA[c];
        unsigned char* cB = lB[c];
        float4 nv0, nv1;
        if (t < 63) {
            nv0 = *(const float4*)(bsrc + (t + 1) * 32);
            nv1 = *(const float4*)(bsrc + (t + 1) * 32 + 4);
            #pragma unroll
            for (int it = 0; it < 5; ++it)
                gload16(asrc[it] + (t + 1) * 32, &lA[c ^ 1][(wv * 320 + it * 64) * 16]);
        }

        short8 afr[5], bfr[4];
        #pragma unroll
        for (int mf = 0; mf < 5; ++mf)
            afr[mf] = *(const short8*)(cA + (lk * 320 + wv * 80 + mf * 16 + lr) * 16);
        #pragma unroll
        for (int n = 0; n < 4; ++n)
            bfr[n] = *(const short8*)(cB + (n * 16 + lr) * 80 + lk * 16);
        #pragma unroll
        for (int mf = 0; mf < 5; ++mf)
            #pragma unroll
            for (int n = 0; n < 4; ++n)
                acc[mf][n] = __builtin_amdgcn_mfma_f32_16x16x32_bf16(afr[mf], bfr[n], acc[mf][n], 0, 0, 0);

        if (t < 63)
            *(short8*)(&lB[c ^ 1][bj * 80 + bp * 16]) = cvt8(nv0, nv1);
        __syncthreads();
    }

    #pragma unroll
    for (int n = 0; n < 2; ++n) {
        const int i = i0 + n * 16 + lr;
        const float ba = b1[(size_t)e * (2 * IDIM) + 2 * i];
        const float bb = b1[(size_t)e * (2 * IDIM) + 2 * i + 1];
        #pragma unroll
        for (int mf = 0; mf < 5; ++mf) {
            #pragma unroll
            for (int r = 0; r < 4; ++r) {
                const int rg = brow + wv * 80 + mf * 16 + lk * 4 + r;
                if (rg < ne) {
                    float ha = acc[mf][n][r] + ba;
                    float hb = acc[mf][n + 2][r] + bb;
                    float a = fminf(ha, LIMIT_C);
                    float b = fminf(fmaxf(hb, -LIMIT_C), LIMIT_C);
                    float s = 1.f / (1.f + __expf(-ALPHA_C * a));
                    act[(size_t)(roff + rg) * IDIM + i] = f2bf(a * s * (b + 1.f));
                }
            }
        }
    }
}

// ---------------- GEMM2 + bias, gate-scale, atomic combine ----------------
__global__ __launch_bounds__(256, 3) void k_gemm2(
    const unsigned short* __restrict__ act,
    const float* __restrict__ w2, const float* __restrict__ b2,
    const int* __restrict__ counts, const int* __restrict__ offsets,
    const int* __restrict__ token_of, const float* __restrict__ gate_row,
    float* __restrict__ out)
{
    __shared__ unsigned char lA[2][20480];
    __shared__ unsigned char lB[2][5120];

    const int e  = blockIdx.z;
    const int ne = counts[e];
    const int brow = blockIdx.y * 320;
    if (brow >= ne) return;
    const int roff = offsets[e];
    const int ks = blockIdx.x & 1;
    const int d0 = (blockIdx.x >> 1) * 64;
    const int kbeg = ks * (IDIM / 2);
    const int tid = threadIdx.x;

    const int wv = tid >> 6, ln = tid & 63;
    const int lr = ln & 15, lk = ln >> 4;
    const int bj = tid >> 2, bp = tid & 3;

    const unsigned short* asrc[5];
    #pragma unroll
    for (int it = 0; it < 5; ++it) {
        int rr = brow + it * 64 + ln;
        int rc = (rr < ne) ? rr : 0;
        asrc[it] = act + (size_t)(roff + rc) * IDIM + kbeg + wv * 8;
    }
    const float* bsrc = w2 + ((size_t)e * HDIM + d0 + bj) * IDIM + kbeg + bp * 8;

    f32x4 acc[5][4] = {};

    {
        float4 v0 = *(const float4*)(bsrc);
        float4 v1 = *(const float4*)(bsrc + 4);
        #pragma unroll
        for (int it = 0; it < 5; ++it)
            gload16(asrc[it], &lA[0][(wv * 320 + it * 64) * 16]);
        *(short8*)(&lB[0][bj * 80 + bp * 16]) = cvt8(v0, v1);
    }
    __syncthreads();

    for (int t = 0; t < 32; ++t) {
        const int c = t & 1;
        unsigned char* cA = lA[c];
        unsigned char* cB = lB[c];
        float4 nv0, nv1;
        if (t < 31) {
            nv0 = *(const float4*)(bsrc + (t + 1) * 32);
            nv1 = *(const float4*)(bsrc + (t + 1) * 32 + 4);
            #pragma unroll
            for (int it = 0; it < 5; ++it)
                gload16(asrc[it] + (t + 1) * 32, &lA[c ^ 1][(wv * 320 + it * 64) * 16]);
        }

        short8 afr[5], bfr[4];
        #pragma unroll
        for (int mf = 0; mf < 5; ++mf)
            afr[mf] = *(const short8*)(cA + (lk * 320 + wv * 80 + mf * 16 + lr) * 16);
        #pragma unroll
        for (int n = 0; n < 4; ++n)
            bfr[n] = *(const short8*)(cB + (n * 16 + lr) * 80 + lk * 16);
        #pragma unroll
        for (int mf = 0; mf < 5; ++mf)
            #pragma unroll
            for (int n = 0; n < 4; ++n)
                acc[mf][n] = __builtin_amdgcn_mfma_f32_16x16x32_bf16(afr[mf], bfr[n], acc[mf][n], 0, 0, 0);

        if (t < 31)
            *(short8*)(&lB[c ^ 1][bj * 80 + bp * 16]) = cvt8(nv0, nv1);
        __syncthreads();
    }

    #pragma unroll
    for (int mf = 0; mf < 5; ++mf) {
        #pragma unroll
        for (int r = 0; r < 4; ++r) {
            const int rg = brow + wv * 80 + mf * 16 + lk * 4 + r;
            if (rg >= ne) continue;
            const int tok = token_of[roff + rg];
            const float g = gate_row[roff + rg];
            float* orow = out + (size_t)tok * HDIM;
            #pragma unroll
            for (int n = 0; n < 4; ++n) {
                const int d = d0 + n * 16 + lr;
                float v = g * acc[mf][n][r];
                if (ks == 0) v += g * b2[(size_t)e * HDIM + d];
                atomicAdd(orow + d, v);
            }
        }
    }
}

extern "C" void kernel_launch(void* const* d_in, const int* in_sizes, int n_in,
                              void* d_out, int out_size, void* d_ws, size_t ws_size,
                              hipStream_t stream) {
    const float* x      = (const float*)d_in[0];
    const float* norm_w = (const float*)d_in[1];
    const float* gate_w = (const float*)d_in[2];
    const float* gate_b = (const float*)d_in[3];
    const float* w1     = (const float*)d_in[4];
    const float* b1     = (const float*)d_in[5];
    const float* w2     = (const float*)d_in[6];
    const float* b2     = (const float*)d_in[7];
    float* out = (float*)d_out;

    char* ws = (char*)d_ws;
    size_t off = 0;
    unsigned short* t_bf = (unsigned short*)(ws + off); off += (size_t)MTOK * HDIM * 2;  // 4 MB
    unsigned short* actb = (unsigned short*)(ws + off); off += (size_t)NA * IDIM * 2;    // 16.8 MB
    int*   counts   = (int*)(ws + off);   off += 256;
    int*   offsets  = (int*)(ws + off);   off += 256;
    int*   idx_of   = (int*)(ws + off);   off += (size_t)NA * 4;
    int*   slot_of  = (int*)(ws + off);   off += (size_t)NA * 4;
    float* gate_mk  = (float*)(ws + off); off += (size_t)NA * 4;
    int*   token_of = (int*)(ws + off);   off += (size_t)NA * 4;
    float* gate_row = (float*)(ws + off); off += (size_t)NA * 4;

    (void)hipMemsetAsync(counts, 0, 256, stream);
    k_copy<<<1024, 256, 0, stream>>>(x, out, MTOK * HDIM / 4);
    k_router<<<MTOK, 256, 0, stream>>>(x, norm_w, gate_w, gate_b, t_bf,
                                       counts, idx_of, slot_of, gate_mk);
    k_offsets<<<1, 64, 0, stream>>>(counts, offsets);
    k_remap<<<NA / 256, 256, 0, stream>>>(idx_of, slot_of, gate_mk, offsets,
                                          token_of, gate_row);
    k_gemm1<<<dim3(IDIM / 32, (MTOK + 319) / 320, NEXP), 256, 0, stream>>>(
        t_bf, w1, b1, counts, offsets, token_of, actb);
    k_gemm2<<<dim3((HDIM / 64) * 2, (MTOK + 319) / 320, NEXP), 256, 0, stream>>>(
        actb, w2, b2, counts, offsets, token_of, gate_row, out);
}

// Round 5
// 464.582 us; speedup vs baseline: 1.3871x; 1.3298x over previous
//
#include <hip/hip_runtime.h>
#include <hip/hip_bf16.h>

constexpr int MTOK = 1024;   // B*S
constexpr int HDIM = 2048;
constexpr int IDIM = 2048;
constexpr int NEXP = 16;
constexpr int TOPK = 4;
constexpr int NA   = MTOK * TOPK;   // 4096 assignments

#define ALPHA_C 1.702f
#define LIMIT_C 7.0f
#define RMS_EPS 1e-5f

using short8   = __attribute__((ext_vector_type(8))) short;
using f32x4    = __attribute__((ext_vector_type(4))) float;

__device__ __forceinline__ unsigned short f2bf(float f) {
    unsigned u = __builtin_bit_cast(unsigned, f);
    u += 0x7fffu + ((u >> 16) & 1u);     // round-to-nearest-even
    return (unsigned short)(u >> 16);
}

__device__ __forceinline__ unsigned pack2bf(float lo, float hi) {
    return (unsigned)f2bf(lo) | ((unsigned)f2bf(hi) << 16);
}

// pack 8 f32 -> 8 bf16 (RNE)
__device__ __forceinline__ short8 cvt8(const float4 a, const float4 b) {
    union { short8 s; unsigned u[4]; } r;
    r.u[0] = pack2bf(a.x, a.y);
    r.u[1] = pack2bf(a.z, a.w);
    r.u[2] = pack2bf(b.x, b.y);
    r.u[3] = pack2bf(b.z, b.w);
    return r.s;
}

// ---------------- out = x ----------------
__global__ void k_copy(const float* __restrict__ x, float* __restrict__ out, int n4) {
    int i = blockIdx.x * blockDim.x + threadIdx.x;
    int stride = gridDim.x * blockDim.x;
    const float4* xs = (const float4*)x;
    float4* os = (float4*)out;
    for (; i < n4; i += stride) os[i] = xs[i];
}

// ---------------- RMSNorm + router + top-k ----------------
__global__ __launch_bounds__(256) void k_router(
    const float* __restrict__ x, const float* __restrict__ norm_w,
    const float* __restrict__ gate_w, const float* __restrict__ gate_b,
    unsigned short* __restrict__ t_bf,
    int* __restrict__ counts, int* __restrict__ idx_of,
    int* __restrict__ slot_of, float* __restrict__ gate_mk)
{
    __shared__ float t_lds[HDIM];
    __shared__ float red[4];
    __shared__ float logits[NEXP];

    const int m   = blockIdx.x;
    const int tid = threadIdx.x;
    const float* xr = x + (size_t)m * HDIM;

    float4 v0 = ((const float4*)xr)[tid * 2];
    float4 v1 = ((const float4*)xr)[tid * 2 + 1];
    float ss = v0.x*v0.x + v0.y*v0.y + v0.z*v0.z + v0.w*v0.w
             + v1.x*v1.x + v1.y*v1.y + v1.z*v1.z + v1.w*v1.w;
    #pragma unroll
    for (int off = 32; off > 0; off >>= 1) ss += __shfl_down(ss, off);
    if ((tid & 63) == 0) red[tid >> 6] = ss;
    __syncthreads();
    float tot = red[0] + red[1] + red[2] + red[3];
    float scale = rsqrtf(tot / (float)HDIM + RMS_EPS);

    float4 n0 = ((const float4*)norm_w)[tid * 2];
    float4 n1 = ((const float4*)norm_w)[tid * 2 + 1];
    float t[8];
    t[0]=v0.x*scale*n0.x; t[1]=v0.y*scale*n0.y; t[2]=v0.z*scale*n0.z; t[3]=v0.w*scale*n0.w;
    t[4]=v1.x*scale*n1.x; t[5]=v1.y*scale*n1.y; t[6]=v1.z*scale*n1.z; t[7]=v1.w*scale*n1.w;
    short8 pk;
    #pragma unroll
    for (int j = 0; j < 8; ++j) {
        t_lds[tid * 8 + j] = t[j];
        pk[j] = (short)f2bf(t[j]);
    }
    *(short8*)(t_bf + (size_t)m * HDIM + tid * 8) = pk;
    __syncthreads();

    const int e = tid >> 4, j = tid & 15;
    const float* gw = gate_w + (size_t)e * HDIM;
    float part = 0.f;
    for (int h = j; h < HDIM; h += 16) part += t_lds[h] * gw[h];
    #pragma unroll
    for (int off = 8; off > 0; off >>= 1) part += __shfl_xor(part, off);
    if (j == 0) logits[e] = part + gate_b[e];
    __syncthreads();

    if (tid == 0) {
        float lv[NEXP];
        #pragma unroll
        for (int q = 0; q < NEXP; ++q) lv[q] = logits[q];
        int   sel[TOPK];
        float sv[TOPK];
        #pragma unroll
        for (int k = 0; k < TOPK; ++k) {
            float best = -1e30f; int bi = 0;
            for (int q = 0; q < NEXP; ++q)
                if (lv[q] > best) { best = lv[q]; bi = q; }
            sel[k] = bi; sv[k] = best; lv[bi] = -1e30f;
        }
        float mx = sv[0], s = 0.f, g[TOPK];
        #pragma unroll
        for (int k = 0; k < TOPK; ++k) { g[k] = __expf(sv[k] - mx); s += g[k]; }
        float inv = 1.f / s;
        #pragma unroll
        for (int k = 0; k < TOPK; ++k) {
            int a = m * TOPK + k;
            int slot = atomicAdd(&counts[sel[k]], 1);
            idx_of[a]  = sel[k];
            slot_of[a] = slot;
            gate_mk[a] = g[k] * inv;
        }
    }
}

__global__ void k_offsets(const int* __restrict__ counts, int* __restrict__ offsets) {
    if (threadIdx.x == 0) {
        int s = 0;
        for (int e = 0; e < NEXP; ++e) { offsets[e] = s; s += counts[e]; }
        offsets[NEXP] = s;
    }
}

__global__ void k_remap(const int* __restrict__ idx_of, const int* __restrict__ slot_of,
                        const float* __restrict__ gate_mk, const int* __restrict__ offsets,
                        int* __restrict__ token_of, float* __restrict__ gate_row)
{
    int a = blockIdx.x * blockDim.x + threadIdx.x;
    if (a >= NA) return;
    int e = idx_of[a];
    int r = offsets[e] + slot_of[a];
    token_of[r] = a >> 2;
    gate_row[r] = gate_mk[a];
}

// ---------------- GEMM1 + bias + clamped SwiGLU -> act (bf16) ----------------
// BM=320 rows; 4 waves; wave wv: rows [wv*80, wv*80+80) x 64 o-cols.
// Reg-staged depth-2 pipeline; raw s_barrier + lgkmcnt-only sync so global
// loads for tile t+2 stay in flight across the barrier (no vmcnt(0) drain).
// lA: [kc(4)][row(320)][16B]; lB: [64][80B].
__global__ __launch_bounds__(256) void k_gemm1(
    const unsigned short* __restrict__ t_bf,
    const float* __restrict__ w1, const float* __restrict__ b1,
    const int* __restrict__ counts, const int* __restrict__ offsets,
    const int* __restrict__ token_of,
    unsigned short* __restrict__ act)
{
    __shared__ unsigned char lA[2][20480];
    __shared__ unsigned char lB[2][5120];

    const int e  = blockIdx.z;
    const int ne = counts[e];
    const int brow = blockIdx.y * 320;
    if (brow >= ne) return;
    const int roff = offsets[e];
    const int i0 = blockIdx.x * 32;
    const int tid = threadIdx.x;

    const int wv = tid >> 6, ln = tid & 63;
    const int lr = ln & 15, lk = ln >> 4;
    const int ar = tid >> 2, ap = tid & 3;   // staging: row ar(+64it), 16B chunk ap

    const unsigned short* asrc[5];
    #pragma unroll
    for (int it = 0; it < 5; ++it) {
        int rr = brow + ar + it * 64;
        int tok = token_of[roff + (rr < ne ? rr : 0)];
        asrc[it] = t_bf + (size_t)tok * HDIM + ap * 8;
    }
    const int o = (ar < 32) ? (2 * (i0 + ar)) : (2 * (i0 + ar - 32) + 1);
    const float* bsrc = w1 + ((size_t)e * (2 * IDIM) + o) * HDIM + ap * 8;

    short8 aR[5];
    float4 bR0, bR1;

    f32x4 acc[5][4] = {};

    // prologue: load t0, publish buf0, issue t1 loads, sync
    #pragma unroll
    for (int it = 0; it < 5; ++it) aR[it] = *(const short8*)(asrc[it]);
    bR0 = *(const float4*)(bsrc);
    bR1 = *(const float4*)(bsrc + 4);
    #pragma unroll
    for (int it = 0; it < 5; ++it)
        *(short8*)(&lA[0][(ap * 320 + ar + it * 64) * 16]) = aR[it];
    *(short8*)(&lB[0][ar * 80 + ap * 16]) = cvt8(bR0, bR1);
    #pragma unroll
    for (int it = 0; it < 5; ++it) aR[it] = *(const short8*)(asrc[it] + 32);
    bR0 = *(const float4*)(bsrc + 32);
    bR1 = *(const float4*)(bsrc + 32 + 4);
    asm volatile("s_waitcnt lgkmcnt(0)" ::: "memory");
    __builtin_amdgcn_s_barrier();

    for (int t = 0; t < 64; ++t) {
        const int c = t & 1;
        // 1) publish tile t+1 (compiler waits exactly on aR/bR loads)
        if (t + 1 < 64) {
            #pragma unroll
            for (int it = 0; it < 5; ++it)
                *(short8*)(&lA[c ^ 1][(ap * 320 + ar + it * 64) * 16]) = aR[it];
            *(short8*)(&lB[c ^ 1][ar * 80 + ap * 16]) = cvt8(bR0, bR1);
        }
        // 2) issue tile t+2 loads (in flight across the barrier)
        if (t + 2 < 64) {
            #pragma unroll
            for (int it = 0; it < 5; ++it)
                aR[it] = *(const short8*)(asrc[it] + (t + 2) * 32);
            bR0 = *(const float4*)(bsrc + (t + 2) * 32);
            bR1 = *(const float4*)(bsrc + (t + 2) * 32 + 4);
        }
        // 3) compute tile t
        short8 afr[5], bfr[4];
        #pragma unroll
        for (int mf = 0; mf < 5; ++mf)
            afr[mf] = *(const short8*)(&lA[c][(lk * 320 + wv * 80 + mf * 16 + lr) * 16]);
        #pragma unroll
        for (int n = 0; n < 4; ++n)
            bfr[n] = *(const short8*)(&lB[c][(n * 16 + lr) * 80 + lk * 16]);
        #pragma unroll
        for (int mf = 0; mf < 5; ++mf)
            #pragma unroll
            for (int n = 0; n < 4; ++n)
                acc[mf][n] = __builtin_amdgcn_mfma_f32_16x16x32_bf16(afr[mf], bfr[n], acc[mf][n], 0, 0, 0);
        // 4) sync: LDS-only drain, vmem stays in flight
        asm volatile("s_waitcnt lgkmcnt(0)" ::: "memory");
        __builtin_amdgcn_s_barrier();
    }

    #pragma unroll
    for (int n = 0; n < 2; ++n) {
        const int i = i0 + n * 16 + lr;
        const float ba = b1[(size_t)e * (2 * IDIM) + 2 * i];
        const float bb = b1[(size_t)e * (2 * IDIM) + 2 * i + 1];
        #pragma unroll
        for (int mf = 0; mf < 5; ++mf) {
            #pragma unroll
            for (int r = 0; r < 4; ++r) {
                const int rg = brow + wv * 80 + mf * 16 + lk * 4 + r;
                if (rg < ne) {
                    float ha = acc[mf][n][r] + ba;
                    float hb = acc[mf][n + 2][r] + bb;
                    float a = fminf(ha, LIMIT_C);
                    float b = fminf(fmaxf(hb, -LIMIT_C), LIMIT_C);
                    float s = 1.f / (1.f + __expf(-ALPHA_C * a));
                    act[(size_t)(roff + rg) * IDIM + i] = f2bf(a * s * (b + 1.f));
                }
            }
        }
    }
}

// ---------------- GEMM2 + bias, gate-scale, atomic combine ----------------
__global__ __launch_bounds__(256) void k_gemm2(
    const unsigned short* __restrict__ act,
    const float* __restrict__ w2, const float* __restrict__ b2,
    const int* __restrict__ counts, const int* __restrict__ offsets,
    const int* __restrict__ token_of, const float* __restrict__ gate_row,
    float* __restrict__ out)
{
    __shared__ unsigned char lA[2][20480];
    __shared__ unsigned char lB[2][5120];

    const int e  = blockIdx.z;
    const int ne = counts[e];
    const int brow = blockIdx.y * 320;
    if (brow >= ne) return;
    const int roff = offsets[e];
    const int ks = blockIdx.x & 1;
    const int d0 = (blockIdx.x >> 1) * 64;
    const int kbeg = ks * (IDIM / 2);
    const int tid = threadIdx.x;

    const int wv = tid >> 6, ln = tid & 63;
    const int lr = ln & 15, lk = ln >> 4;
    const int ar = tid >> 2, ap = tid & 3;

    const unsigned short* asrc[5];
    #pragma unroll
    for (int it = 0; it < 5; ++it) {
        int rr = brow + ar + it * 64;
        int rc = (rr < ne) ? rr : 0;
        asrc[it] = act + (size_t)(roff + rc) * IDIM + kbeg + ap * 8;
    }
    const float* bsrc = w2 + ((size_t)e * HDIM + d0 + ar) * IDIM + kbeg + ap * 8;

    short8 aR[5];
    float4 bR0, bR1;

    f32x4 acc[5][4] = {};

    #pragma unroll
    for (int it = 0; it < 5; ++it) aR[it] = *(const short8*)(asrc[it]);
    bR0 = *(const float4*)(bsrc);
    bR1 = *(const float4*)(bsrc + 4);
    #pragma unroll
    for (int it = 0; it < 5; ++it)
        *(short8*)(&lA[0][(ap * 320 + ar + it * 64) * 16]) = aR[it];
    *(short8*)(&lB[0][ar * 80 + ap * 16]) = cvt8(bR0, bR1);
    #pragma unroll
    for (int it = 0; it < 5; ++it) aR[it] = *(const short8*)(asrc[it] + 32);
    bR0 = *(const float4*)(bsrc + 32);
    bR1 = *(const float4*)(bsrc + 32 + 4);
    asm volatile("s_waitcnt lgkmcnt(0)" ::: "memory");
    __builtin_amdgcn_s_barrier();

    for (int t = 0; t < 32; ++t) {
        const int c = t & 1;
        if (t + 1 < 32) {
            #pragma unroll
            for (int it = 0; it < 5; ++it)
                *(short8*)(&lA[c ^ 1][(ap * 320 + ar + it * 64) * 16]) = aR[it];
            *(short8*)(&lB[c ^ 1][ar * 80 + ap * 16]) = cvt8(bR0, bR1);
        }
        if (t + 2 < 32) {
            #pragma unroll
            for (int it = 0; it < 5; ++it)
                aR[it] = *(const short8*)(asrc[it] + (t + 2) * 32);
            bR0 = *(const float4*)(bsrc + (t + 2) * 32);
            bR1 = *(const float4*)(bsrc + (t + 2) * 32 + 4);
        }
        short8 afr[5], bfr[4];
        #pragma unroll
        for (int mf = 0; mf < 5; ++mf)
            afr[mf] = *(const short8*)(&lA[c][(lk * 320 + wv * 80 + mf * 16 + lr) * 16]);
        #pragma unroll
        for (int n = 0; n < 4; ++n)
            bfr[n] = *(const short8*)(&lB[c][(n * 16 + lr) * 80 + lk * 16]);
        #pragma unroll
        for (int mf = 0; mf < 5; ++mf)
            #pragma unroll
            for (int n = 0; n < 4; ++n)
                acc[mf][n] = __builtin_amdgcn_mfma_f32_16x16x32_bf16(afr[mf], bfr[n], acc[mf][n], 0, 0, 0);
        asm volatile("s_waitcnt lgkmcnt(0)" ::: "memory");
        __builtin_amdgcn_s_barrier();
    }

    #pragma unroll
    for (int mf = 0; mf < 5; ++mf) {
        #pragma unroll
        for (int r = 0; r < 4; ++r) {
            const int rg = brow + wv * 80 + mf * 16 + lk * 4 + r;
            if (rg >= ne) continue;
            const int tok = token_of[roff + rg];
            const float g = gate_row[roff + rg];
            float* orow = out + (size_t)tok * HDIM;
            #pragma unroll
            for (int n = 0; n < 4; ++n) {
                const int d = d0 + n * 16 + lr;
                float v = g * acc[mf][n][r];
                if (ks == 0) v += g * b2[(size_t)e * HDIM + d];
                atomicAdd(orow + d, v);
            }
        }
    }
}

extern "C" void kernel_launch(void* const* d_in, const int* in_sizes, int n_in,
                              void* d_out, int out_size, void* d_ws, size_t ws_size,
                              hipStream_t stream) {
    const float* x      = (const float*)d_in[0];
    const float* norm_w = (const float*)d_in[1];
    const float* gate_w = (const float*)d_in[2];
    const float* gate_b = (const float*)d_in[3];
    const float* w1     = (const float*)d_in[4];
    const float* b1     = (const float*)d_in[5];
    const float* w2     = (const float*)d_in[6];
    const float* b2     = (const float*)d_in[7];
    float* out = (float*)d_out;

    char* ws = (char*)d_ws;
    size_t off = 0;
    unsigned short* t_bf = (unsigned short*)(ws + off); off += (size_t)MTOK * HDIM * 2;  // 4 MB
    unsigned short* actb = (unsigned short*)(ws + off); off += (size_t)NA * IDIM * 2;    // 16.8 MB
    int*   counts   = (int*)(ws + off);   off += 256;
    int*   offsets  = (int*)(ws + off);   off += 256;
    int*   idx_of   = (int*)(ws + off);   off += (size_t)NA * 4;
    int*   slot_of  = (int*)(ws + off);   off += (size_t)NA * 4;
    float* gate_mk  = (float*)(ws + off); off += (size_t)NA * 4;
    int*   token_of = (int*)(ws + off);   off += (size_t)NA * 4;
    float* gate_row = (float*)(ws + off); off += (size_t)NA * 4;

    (void)hipMemsetAsync(counts, 0, 256, stream);
    k_copy<<<1024, 256, 0, stream>>>(x, out, MTOK * HDIM / 4);
    k_router<<<MTOK, 256, 0, stream>>>(x, norm_w, gate_w, gate_b, t_bf,
                                       counts, idx_of, slot_of, gate_mk);
    k_offsets<<<1, 64, 0, stream>>>(counts, offsets);
    k_remap<<<NA / 256, 256, 0, stream>>>(idx_of, slot_of, gate_mk, offsets,
                                          token_of, gate_row);
    k_gemm1<<<dim3(IDIM / 32, (MTOK + 319) / 320, NEXP), 256, 0, stream>>>(
        t_bf, w1, b1, counts, offsets, token_of, actb);
    k_gemm2<<<dim3((HDIM / 64) * 2, (MTOK + 319) / 320, NEXP), 256, 0, stream>>>(
        actb, w2, b2, counts, offsets, token_of, gate_row, out);
}